// Round 1
// baseline (5196.052 us; speedup 1.0000x reference)
//
#include <hip/hip_runtime.h>

typedef unsigned short u16;
typedef unsigned int u32;
typedef __attribute__((ext_vector_type(8))) short short8;
typedef __attribute__((ext_vector_type(4))) float f32x4;

#define NB 256
#define HID2 2048
#define G4 8192
#define K0 2176
#define K1 4096

__device__ __forceinline__ u16 f2b(float f){
  union { float f; u32 u; } v; v.f = f;
  u32 u = v.u;
  u32 r = (u >> 16) & 1u;
  u = u + 0x7fffu + r;
  return (u16)(u >> 16);
}
__device__ __forceinline__ float b2f(u16 h){
  union { u32 u; float f; } v; v.u = ((u32)h) << 16;
  return v.f;
}
__device__ __forceinline__ float sigm(float x){ return 1.0f/(1.0f + __expf(-x)); }
__device__ __forceinline__ float tanh_f(float x){ return 1.0f - 2.0f/(1.0f + __expf(2.0f*x)); }

__device__ __forceinline__ void gload16(const void* g, void* l){
  __builtin_amdgcn_global_load_lds(
      (const __attribute__((address_space(1))) unsigned int*)g,
      (__attribute__((address_space(3))) unsigned int*)l,
      16, 0, 0);
}

// ---------------- prep kernels ----------------

// W0 permuted bf16 [8192][2176]; col 0..95 = w_ih0, 96..127 = 0 pad, 128.. = w_hh0
__global__ void prep_w0(const float* __restrict__ wih, const float* __restrict__ whh,
                        const float* __restrict__ bih, const float* __restrict__ bhh,
                        u16* __restrict__ W0, float* __restrict__ bias0){
  int k = blockIdx.x * 256 + threadIdx.x;
  int n = blockIdx.y;
  if (k >= K0) return;
  int u = ((n >> 6) << 4) | (n & 15);
  int gate = (n >> 4) & 3;
  int r = gate * HID2 + u;
  float v;
  if (k < 96)       v = wih[(size_t)r * 96 + k];
  else if (k < 128) v = 0.0f;
  else              v = whh[(size_t)r * HID2 + (k - 128)];
  W0[(size_t)n * K0 + k] = f2b(v);
  if (k == 0) bias0[n] = bih[r] + bhh[r];
}

// W1 permuted bf16 [8192][4096]; col 0..2047 = w_ih1 (applied to h0n), 2048.. = w_hh1
__global__ void prep_w1(const float* __restrict__ wih, const float* __restrict__ whh,
                        const float* __restrict__ bih, const float* __restrict__ bhh,
                        u16* __restrict__ W1, float* __restrict__ bias1){
  int k = blockIdx.x * 256 + threadIdx.x;
  int n = blockIdx.y;
  int u = ((n >> 6) << 4) | (n & 15);
  int gate = (n >> 4) & 3;
  int r = gate * HID2 + u;
  float v = (k < HID2) ? wih[(size_t)r * HID2 + k] : whh[(size_t)r * HID2 + (k - HID2)];
  W1[(size_t)n * K1 + k] = f2b(v);
  if (k == 0) bias1[n] = bih[r] + bhh[r];
}

// WoutT[96][2048] = weights_out^T (fp32, row contiguous in K)
__global__ void prep_wout(const float* __restrict__ wout, float* __restrict__ WoT){
  int id = blockIdx.x * 256 + threadIdx.x;   // 96*2048
  int n = id >> 11, k = id & 2047;
  WoT[(size_t)n * HID2 + k] = wout[(size_t)k * 96 + n];
}

// h0/h1/c inits
__global__ void prep_state(const float* __restrict__ hs, const float* __restrict__ cs,
                           const float* __restrict__ gts, u16* __restrict__ A0_0,
                           u16* __restrict__ A1_0, float* __restrict__ c0,
                           float* __restrict__ c1i){
  int id = blockIdx.x * 256 + threadIdx.x;   // 256*512 threads, 4 elems each
  int b = id >> 9;
  int j = (id & 511) << 2;
  const float* hp = hs + (size_t)b * 49 * HID2 + j;
  const float* cp = cs + (size_t)b * 49 * HID2 + j;
  float sh[4] = {0,0,0,0}, sc[4] = {0,0,0,0};
  for (int t = 0; t < 49; ++t){
    float4 hv = *(const float4*)(hp + (size_t)t * HID2);
    float4 cv = *(const float4*)(cp + (size_t)t * HID2);
    sh[0]+=hv.x; sh[1]+=hv.y; sh[2]+=hv.z; sh[3]+=hv.w;
    sc[0]+=cv.x; sc[1]+=cv.y; sc[2]+=cv.z; sc[3]+=cv.w;
  }
  float4 gv = *(const float4*)(gts + (size_t)b * HID2 + j);
  float g[4] = {gv.x, gv.y, gv.z, gv.w};
  #pragma unroll
  for (int q = 0; q < 4; ++q){
    float cm = sc[q] / 49.0f;
    c0[(size_t)b * HID2 + j + q]  = cm;
    c1i[(size_t)b * HID2 + j + q] = cm;
    A0_0[(size_t)b * K0 + 128 + j + q] = f2b(sh[q] / 49.0f);
    A1_0[(size_t)b * K1 + HID2 + j + q] = f2b((sh[q] + g[q]) / 50.0f);
  }
}

// x init: A0[0] cols 0..95 = bf16(p), pad cols 96..127 zero in both A0 halves
__global__ void prep_x(const float* __restrict__ p, u16* __restrict__ A0_0,
                       u16* __restrict__ A0_1){
  int id = blockIdx.x * 256 + threadIdx.x;  // 256*128
  int b = id >> 7, j = id & 127;
  u16 v = (j < 96) ? f2b(p[(size_t)b * 96 + j]) : (u16)0;
  A0_0[(size_t)b * K0 + j] = v;
  if (j >= 96) A0_1[(size_t)b * K0 + j] = 0;
}

// ---------------- fused GEMM + LSTM cell ----------------
// gates[m][n] = sum_k A[m][k]*W[n][k]  (+bias), then cell epilogue.
// Permuted N layout: n = (u>>4)*64 + gate*16 + (u&15)
template<int K>
__global__ __launch_bounds__(256) void gemm_cell(
    const u16* __restrict__ A, const u16* __restrict__ W, const float* __restrict__ bias,
    const float* __restrict__ c_in, int ci_rs, float* __restrict__ c_out, int co_rs,
    u16* __restrict__ h0o, int h0_rs, u16* __restrict__ h1o, int h1_rs)
{
  __shared__ u16 ldsA[2][64 * 64];    // 8KB each
  __shared__ u16 ldsB[2][128 * 64];   // 16KB each
  const int tid = threadIdx.x;
  const int id = blockIdx.x;
  // XCD swizzle: the 4 M-tiles of one N-tile land on the same XCD (id%8 assumption)
  const int bx = ((id & 7) << 3) | ((id >> 3) & 7);
  const int by = id >> 6;
  const int m0 = by * 64, n0 = bx * 128;
  const int lane = tid & 63, wid = tid >> 6;
  const int wm = wid & 1, wn = wid >> 1;
  const int l15 = lane & 15, l4 = lane >> 4;
  const int ar = tid >> 3;            // staging row base 0..31
  const int cb = (tid & 7) << 4;      // staging col byte 0..112
  const char* Abase = (const char*)A;
  const char* Wbase = (const char*)W;

  f32x4 acc[2][4];
  #pragma unroll
  for (int i = 0; i < 2; ++i)
    #pragma unroll
    for (int j = 0; j < 4; ++j) acc[i][j] = (f32x4){0.f, 0.f, 0.f, 0.f};

  auto stage = [&](int buf, int kt){
    const size_t kofs = (size_t)kt * 128;
    #pragma unroll
    for (int j = 0; j < 2; ++j){
      int r = ar + j * 32;
      const char* src = Abase + (size_t)(m0 + r) * (K * 2) + kofs + (cb ^ ((r & 7) << 4));
      gload16(src, (char*)&ldsA[buf][0] + j * 4096 + wid * 1024);
    }
    #pragma unroll
    for (int j = 0; j < 4; ++j){
      int r = ar + j * 32;
      const char* src = Wbase + (size_t)(n0 + r) * (K * 2) + kofs + (cb ^ ((r & 7) << 4));
      gload16(src, (char*)&ldsB[buf][0] + j * 4096 + wid * 1024);
    }
  };

  stage(0, 0);
  __syncthreads();
  const int NT = K / 64;
  for (int kt = 0; kt < NT; ++kt){
    const int cur = kt & 1;
    if (kt + 1 < NT) stage(cur ^ 1, kt + 1);
    #pragma unroll
    for (int ks = 0; ks < 2; ++ks){
      short8 af[2], bf[4];
      #pragma unroll
      for (int mf = 0; mf < 2; ++mf){
        int r = wm * 32 + mf * 16 + l15;
        int c = (ks * 64 + (l4 << 4)) ^ ((r & 7) << 4);
        af[mf] = *(const short8*)((const char*)&ldsA[cur][0] + r * 128 + c);
      }
      #pragma unroll
      for (int nf = 0; nf < 4; ++nf){
        int r = wn * 64 + nf * 16 + l15;
        int c = (ks * 64 + (l4 << 4)) ^ ((r & 7) << 4);
        bf[nf] = *(const short8*)((const char*)&ldsB[cur][0] + r * 128 + c);
      }
      #pragma unroll
      for (int mf = 0; mf < 2; ++mf)
        #pragma unroll
        for (int nf = 0; nf < 4; ++nf)
          acc[mf][nf] = __builtin_amdgcn_mfma_f32_16x16x32_bf16(af[mf], bf[nf], acc[mf][nf], 0, 0, 0);
    }
    __syncthreads();
  }

  // epilogue: lane&15 = unit-in-group, nf = gate, rows = m
  const int u = (n0 >> 2) + wn * 16 + l15;
  float bg[4];
  #pragma unroll
  for (int nf = 0; nf < 4; ++nf) bg[nf] = bias[n0 + wn * 64 + nf * 16 + l15];
  #pragma unroll
  for (int mf = 0; mf < 2; ++mf){
    const int mb = m0 + wm * 32 + mf * 16 + (l4 << 2);
    #pragma unroll
    for (int reg = 0; reg < 4; ++reg){
      const int m = mb + reg;
      float gi = acc[mf][0][reg] + bg[0];
      float gf = acc[mf][1][reg] + bg[1];
      float gg = acc[mf][2][reg] + bg[2];
      float go = acc[mf][3][reg] + bg[3];
      float iv = sigm(gi), fv = sigm(gf), ov = sigm(go);
      float gv = tanh_f(gg);
      float co = c_in[(size_t)m * ci_rs + u];
      float cn = fv * co + iv * gv;
      float hn = ov * tanh_f(cn);
      c_out[(size_t)m * co_rs + u] = cn;
      u16 hb = f2b(hn);
      h0o[(size_t)m * h0_rs + u] = hb;
      if (h1o) h1o[(size_t)m * h1_rs + u] = hb;
    }
  }
}

// ---------------- output projection (split-K, 2 kernels) ----------------
__global__ __launch_bounds__(256) void proj_partial(const u16* __restrict__ h1,
                                                    const float* __restrict__ WoT,
                                                    float* __restrict__ part){
  __shared__ float wl[96 * 132];
  __shared__ float hl[16 * 128];
  int kc = blockIdx.x, bt = blockIdx.y;
  int tid = threadIdx.x;
  for (int i = tid; i < 96 * 128; i += 256){
    int n = i >> 7, kk = i & 127;
    wl[n * 132 + kk] = WoT[(size_t)n * HID2 + kc * 128 + kk];
  }
  for (int i = tid; i < 16 * 128; i += 256){
    int bi = i >> 7, kk = i & 127;
    hl[i] = b2f(h1[(size_t)(bt * 16 + bi) * K1 + kc * 128 + kk]);
  }
  __syncthreads();
  int ni0 = tid & 15, bi = tid >> 4;
  float acc[6] = {0, 0, 0, 0, 0, 0};
  for (int kk = 0; kk < 128; kk += 4){
    float4 h4 = *(const float4*)&hl[bi * 128 + kk];
    #pragma unroll
    for (int nn = 0; nn < 6; ++nn){
      int n = ni0 + nn * 16;
      float4 w4 = *(const float4*)&wl[n * 132 + kk];
      acc[nn] += h4.x * w4.x + h4.y * w4.y + h4.z * w4.z + h4.w * w4.w;
    }
  }
  #pragma unroll
  for (int nn = 0; nn < 6; ++nn){
    int n = ni0 + nn * 16;
    part[(size_t)kc * 24576 + (size_t)(bt * 16 + bi) * 96 + n] = acc[nn];
  }
}

__global__ void proj_reduce(const float* __restrict__ part, const float* __restrict__ bout,
                            const float* __restrict__ p, float* __restrict__ out_pre,
                            int t, u16* __restrict__ A0w){
  int id = blockIdx.x * 256 + threadIdx.x;  // 24576
  int b = id / 96, n = id % 96;
  float s = 0.0f;
  #pragma unroll
  for (int kc = 0; kc < 16; ++kc) s += part[(size_t)kc * 24576 + id];
  s += bout[n];
  s += (t == 0) ? p[id] : out_pre[((size_t)b * 50 + (t - 1)) * 96 + n];
  out_pre[((size_t)b * 50 + t) * 96 + n] = s;
  A0w[(size_t)b * K0 + n] = f2b(s);
}

// ---------------- launcher ----------------
extern "C" void kernel_launch(void* const* d_in, const int* in_sizes, int n_in,
                              void* d_out, int out_size, void* d_ws, size_t ws_size,
                              hipStream_t stream){
  const float* hs   = (const float*)d_in[0];
  const float* cs   = (const float*)d_in[1];
  const float* gts  = (const float*)d_in[2];
  const float* p    = (const float*)d_in[4];
  const float* wih0 = (const float*)d_in[6];
  const float* whh0 = (const float*)d_in[7];
  const float* bih0 = (const float*)d_in[8];
  const float* bhh0 = (const float*)d_in[9];
  const float* wih1 = (const float*)d_in[10];
  const float* whh1 = (const float*)d_in[11];
  const float* bih1 = (const float*)d_in[12];
  const float* bhh1 = (const float*)d_in[13];
  const float* wout = (const float*)d_in[14];
  const float* bout = (const float*)d_in[15];

  char* w = (char*)d_ws;
  auto take = [&](size_t bytes) -> char* {
    char* r = w; w += (bytes + 255) & ~(size_t)255; return r;
  };
  u16*  W0    = (u16*)take((size_t)G4 * K0 * 2);
  u16*  W1    = (u16*)take((size_t)G4 * K1 * 2);
  float* bias0 = (float*)take((size_t)G4 * 4);
  float* bias1 = (float*)take((size_t)G4 * 4);
  u16*  A0    = (u16*)take((size_t)2 * NB * K0 * 2);
  u16*  A1    = (u16*)take((size_t)2 * NB * K1 * 2);
  float* c0    = (float*)take((size_t)NB * HID2 * 4);
  float* c1i   = (float*)take((size_t)NB * HID2 * 4);
  float* WoT   = (float*)take((size_t)96 * HID2 * 4);
  float* part  = (float*)take((size_t)16 * NB * 96 * 4);
  if ((size_t)(w - (char*)d_ws) > ws_size) return;  // ws too small: bail loudly

  const size_t A0sz = (size_t)NB * K0;
  const size_t A1sz = (size_t)NB * K1;
  float* out_pre  = (float*)d_out;                    // [B][50][96]
  float* out_prec = out_pre + (size_t)NB * 50 * 96;   // [B][50][2048]

  prep_w0<<<dim3(9, G4), 256, 0, stream>>>(wih0, whh0, bih0, bhh0, W0, bias0);
  prep_w1<<<dim3(16, G4), 256, 0, stream>>>(wih1, whh1, bih1, bhh1, W1, bias1);
  prep_wout<<<768, 256, 0, stream>>>(wout, WoT);
  prep_state<<<512, 256, 0, stream>>>(hs, cs, gts, A0, A1, c0, c1i);
  prep_x<<<128, 256, 0, stream>>>(p, A0, A0 + A0sz);

  for (int t = 0; t < 50; ++t){
    u16* A0r = A0 + (size_t)(t & 1) * A0sz;
    u16* A0w = A0 + (size_t)((t + 1) & 1) * A0sz;
    u16* A1r = A1 + (size_t)(t & 1) * A1sz;
    u16* A1w = A1 + (size_t)((t + 1) & 1) * A1sz;

    // layer 0: reads A0r=[x|pad|h0], writes h0n -> A1r cols 0.. and A0w cols 128..
    gemm_cell<K0><<<256, 256, 0, stream>>>(A0r, W0, bias0,
        c0, HID2, c0, HID2,
        A1r, K1, A0w + 128, K0);

    // layer 1: reads A1r=[h0n|h1], c1 state lives in out_prec slices
    const float* c1in = t ? (const float*)(out_prec + (size_t)(t - 1) * HID2) : c1i;
    int c1in_rs = t ? 50 * HID2 : HID2;
    gemm_cell<K1><<<256, 256, 0, stream>>>(A1r, W1, bias1,
        c1in, c1in_rs, out_prec + (size_t)t * HID2, 50 * HID2,
        A1w + HID2, K1, (u16*)nullptr, 0);

    // projection: pre = h1n @ Wout + bias_out + prev
    proj_partial<<<dim3(16, 16), 256, 0, stream>>>(A1w + HID2, WoT, part);
    proj_reduce<<<96, 256, 0, stream>>>(part, bout, p, out_pre, t, A0w);
  }
}